// Round 11
// baseline (2307.391 us; speedup 1.0000x reference)
//
#include <hip/hip_runtime.h>
#include <hip/hip_bf16.h>
#include <stdint.h>

// Problem constants (LSTM_36825049596199)
#define B_    64
#define T_    512
#define EMB_  128
#define H_    128
#define G4    512            // 4*H
#define M_    (B_ * T_)      // 32768 rows for the input-projection GEMM

typedef __attribute__((ext_vector_type(8))) short     short8;   // 8 bf16 MFMA frag
typedef __attribute__((ext_vector_type(4))) float     floatx4;  // MFMA acc frag
typedef __attribute__((ext_vector_type(2))) _Float16  half2v;   // packed f16 (v_dot2)

#define GLDS(g, l) __builtin_amdgcn_global_load_lds( \
    (__attribute__((address_space(1))) void*)(g),    \
    (__attribute__((address_space(3))) void*)(l), 16, 0, 0)

__device__ __forceinline__ unsigned short f2bf_bits(float f) {
  __hip_bfloat16 h = __float2bfloat16(f);
  return *reinterpret_cast<unsigned short*>(&h);
}
__device__ __forceinline__ float bf_bits2f(unsigned short u) {
  unsigned int x = ((unsigned int)u) << 16;
  return __uint_as_float(x);
}
__device__ __forceinline__ float sigm(float x) {
  return __fdividef(1.0f, 1.0f + __expf(-x));
}
__device__ __forceinline__ float tanh_fast(float x) {
  return 1.0f - __fdividef(2.0f, __expf(2.0f * x) + 1.0f);
}

__device__ __forceinline__ unsigned int pack_f16x2(float a, float b) {
  half2v h; h.x = (_Float16)a; h.y = (_Float16)b;
  return __builtin_bit_cast(unsigned int, h);
}
__device__ __forceinline__ half2v u2h2(unsigned int u) {
  return __builtin_bit_cast(half2v, u);
}

#if __has_builtin(__builtin_amdgcn_fdot2)
__device__ __forceinline__ float fdot2(half2v a, half2v b, float c) {
  return __builtin_amdgcn_fdot2(a, b, c, false);   // v_dot2_f32_f16, fp32 acc
}
#else
__device__ __forceinline__ float fdot2(half2v a, half2v b, float c) {
  return fmaf((float)a.x, (float)b.x, fmaf((float)a.y, (float)b.y, c));
}
#endif

// Butterfly sum across a quad — pure VALU DPP (no DS pipe).
__device__ __forceinline__ float quad_bfly_add(float x) {
  float y = x + __int_as_float(
      __builtin_amdgcn_mov_dpp(__float_as_int(x), 0xB1, 0xF, 0xF, true));
  return y + __int_as_float(
      __builtin_amdgcn_mov_dpp(__float_as_int(y), 0x4E, 0xF, 0xF, true));
}

// LDS-only barrier (precise builtins; R8-verified equivalent to
// __syncthreads here). 0xC07F: vmcnt=63, expcnt=7, lgkmcnt=0.
__device__ __forceinline__ void barrier_lds_only() {
  __builtin_amdgcn_s_waitcnt(0xC07F);
  __builtin_amdgcn_s_barrier();
}

// xg element type templated: float (precise) if workspace allows, bf16 otherwise.
__device__ __forceinline__ void  store_xg(float* p, float v)  { *p = v; }
__device__ __forceinline__ void  store_xg(unsigned short* p, float v) { *p = f2bf_bits(v); }
__device__ __forceinline__ float load_xg(const float* p)  { return *p; }
__device__ __forceinline__ float load_xg(const unsigned short* p) { return bf_bits2f(*p); }

// ---------------------------------------------------------------------------
// Embedding gather: x0[b,t,:] = bf16(emb[X[b,t],:]).
__global__ void k_gather(const int* __restrict__ X, const float* __restrict__ emb,
                         unsigned short* __restrict__ x0) {
  int i = blockIdx.x * 256 + threadIdx.x;
  int row = i >> 5, c4 = i & 31;
  float4 v = ((const float4*)emb)[(size_t)X[row] * 32 + c4];
  ushort4 o;
  o.x = f2bf_bits(v.x); o.y = f2bf_bits(v.y); o.z = f2bf_bits(v.z); o.w = f2bf_bits(v.w);
  ((ushort4*)x0)[i] = o;
}

// Per-layer prep: w_ih -> bf16, bias_sum = b_ih + b_hh.
__global__ void k_prep(const float* __restrict__ w, const float* __restrict__ bi,
                       const float* __restrict__ bh, unsigned short* __restrict__ wb,
                       float* __restrict__ bias, int nw) {
  int i = blockIdx.x * blockDim.x + threadIdx.x;
  int stride = gridDim.x * blockDim.x;
  for (int k = i; k < nw; k += stride) wb[k] = f2bf_bits(w[k]);
  for (int k = i; k < 2 * G4; k += stride) bias[k] = bi[k] + bh[k];
}

// W_hh f16-pack into the scan's lane-coalesced layout (unchanged from R6).
__global__ void k_prep_whh(const float* __restrict__ Whh, unsigned int* __restrict__ wf) {
  int i = blockIdx.x * 256 + threadIdx.x;          // [0, 65536)
  int dir = i >> 15;
  int t2  = i & 0x7FFF;
  int jq  = t2 >> 11;
  int t3  = t2 & 0x7FF;
  int ts  = t3 >> 2;
  int q   = t3 & 3;
  int d   = jq * 4 + q;
  int g   = d >> 4;
  int jj  = d & 15;
  int lane = ts & 63, wave = ts >> 6;
  int p = lane & 3, ul = lane >> 2;
  int u = wave * 16 + ul;
  int k = 32 * p + 2 * jj;
  const float* wr = Whh + ((size_t)dir * G4 + g * H_ + u) * H_ + k;
  wf[i] = pack_f16x2(wr[0], wr[1]);
}

// ---------------------------------------------------------------------------
// Input-projection GEMM (NT) — R8 version (gate-major xg columns).
template <typename XG_T>
__global__ __launch_bounds__(256, 2) void k_gemm(
    const unsigned short* __restrict__ A,   // [M_, K] bf16 row-major
    const unsigned short* __restrict__ W,   // [2][G4][K] bf16 row-major
    const float* __restrict__ bias,         // [2][G4]
    XG_T* __restrict__ xg,                  // [2][M_][G4]
    int K) {
  __shared__ unsigned short sA[128 * 32];
  __shared__ unsigned short sB[128 * 32];
  const int tid  = threadIdx.x;
  const int lane = tid & 63;
  const int wave = tid >> 6;
  const int mt = blockIdx.x, nt = blockIdx.y, dir = blockIdx.z;
  const size_t Arow0 = (size_t)mt * 128;
  const int    Ncol0 = nt * 128;
  const unsigned short* Wd = W + (size_t)dir * G4 * K;

  const int srow = tid >> 2;
  const int qlog = (tid & 3) ^ ((tid >> 4) & 3);
  auto ldsA0 = (__attribute__((address_space(3))) void*)(sA + wave * 512);
  auto ldsA1 = (__attribute__((address_space(3))) void*)(sA + 2048 + wave * 512);
  auto ldsB0 = (__attribute__((address_space(3))) void*)(sB + wave * 512);
  auto ldsB1 = (__attribute__((address_space(3))) void*)(sB + 2048 + wave * 512);

  floatx4 acc[4][4];
#pragma unroll
  for (int i = 0; i < 4; ++i)
#pragma unroll
    for (int j = 0; j < 4; ++j) acc[i][j] = (floatx4)0.0f;

  const int wrow = (wave >> 1) * 64, wcol = (wave & 1) * 64;
  const int frow = lane & 15;
  const int fq   = lane >> 4;

  for (int kt = 0; kt < K; kt += 32) {
    const unsigned short* gA0 = A  + (Arow0 + srow) * (size_t)K + kt + qlog * 8;
    const unsigned short* gB0 = Wd + (size_t)(Ncol0 + srow) * K + kt + qlog * 8;
    GLDS(gA0, ldsA0);
    GLDS(gA0 + (size_t)64 * K, ldsA1);
    GLDS(gB0, ldsB0);
    GLDS(gB0 + (size_t)64 * K, ldsB1);
    __syncthreads();

    short8 af[4], bf[4];
#pragma unroll
    for (int i = 0; i < 4; ++i) {
      int r  = wrow + 16 * i + frow;
      int rn = wcol + 16 * i + frow;
      af[i] = *(const short8*)(sA + r  * 32 + ((fq ^ ((r  >> 2) & 3)) * 8));
      bf[i] = *(const short8*)(sB + rn * 32 + ((fq ^ ((rn >> 2) & 3)) * 8));
    }
#pragma unroll
    for (int i = 0; i < 4; ++i)
#pragma unroll
      for (int j = 0; j < 4; ++j)
        acc[i][j] = __builtin_amdgcn_mfma_f32_16x16x32_bf16(af[i], bf[j], acc[i][j], 0, 0, 0);
    __syncthreads();
  }

  const int r0 = (lane >> 4) * 4;
  const int cc = lane & 15;
  XG_T* xgd = xg + (size_t)dir * M_ * G4;
#pragma unroll
  for (int j = 0; j < 4; ++j) {
    int gcol = Ncol0 + wcol + 16 * j + cc;
    float bs = bias[dir * G4 + gcol];
#pragma unroll
    for (int i = 0; i < 4; ++i) {
      size_t rowb = Arow0 + wrow + 16 * i + r0;
#pragma unroll
      for (int r = 0; r < 4; ++r)
        store_xg(&xgd[(rowb + r) * G4 + gcol], acc[i][j][r] + bs);
    }
  }
}

// ---------------------------------------------------------------------------
// Recurrent scan — R11: TWO sequences per block (fixed-cost amortization).
// R1-R10 invariant analysis: per-seq step time ~1900 cyc was insensitive to
// barriers/DS/VALU/VMEM changes -> dominated by a FIXED per-step cost of the
// one-seq-per-block lockstep structure (barrier arrival/wake of 8 waves,
// post-barrier LDS latency, and the latency-bound transcendental tail that
// synchronized waves hit simultaneously, so no inter-wave hiding).
// Fix: 1024 threads = 16 waves = 2 sequences (b and b+32, SAME dir -> same
// weight layout). Wave->SIMD round-robin gives each SIMD 2 waves of EACH
// sequence; the sequences have no data dependency, so one seq's tail overlaps
// the other's dots on the same SIMD, and one barrier advances TWO seq-steps.
// Per-seq math/layout bit-identical to R8 (f16 weights VGPR-resident,
// p=lane&3 k-slice, DPP quad reduce, distance-2 xg prefetch).
template <typename XG_T>
__global__ __attribute__((amdgpu_flat_work_group_size(1024, 1024),
                          amdgpu_waves_per_eu(4, 4))) void k_scan(
    const unsigned int* __restrict__ wf,  // [2][16][512][4] packed f16 pairs
    const float* __restrict__ hx0,        // [2][B_][H_] (layer base)
    const float* __restrict__ cx0,
    const XG_T* __restrict__ xg,          // [2][M_][G4]
    unsigned short* __restrict__ y)       // [B_][T_][2*H_] bf16
{
  const int seq = threadIdx.x >> 9;       // 0: waves 0-7, 1: waves 8-15
  const int tid = threadIdx.x & 511;      // within-sequence tid (R8-identical)
  const int b   = (blockIdx.x & 31) + 32 * seq;
  const int dir = blockIdx.x >> 5;
  const int lane = tid & 63;
  const int wave = tid >> 6;              // within-sequence wave 0-7
  const int p  = lane & 3;                // k-slice (32 k each)
  const int ul = lane >> 2;               // unit within wave
  const int u  = wave * 16 + ul;

  __shared__ __align__(16) unsigned short h16[2][2][128];   // [parity][seq][u]

  // Weights: same for both seqs (same dir). 16 coalesced uint4 loads;
  // d = g*16+jj -> wv[d>>2][d&3] = f16 pair (k=32p+2jj, k+1) of gate g.
  uint4 wv[16];
  const uint4* wfv = (const uint4*)wf;
#pragma unroll
  for (int i = 0; i < 16; ++i) wv[i] = wfv[(dir * 16 + i) * 512 + tid];

  float c = cx0[(size_t)dir * B_ * H_ + b * H_ + u];   // replicated over quad
  if (p == 0) {
    float h0 = hx0[(size_t)dir * B_ * H_ + b * H_ + u];
    h16[0][seq][u] = (unsigned short)(pack_f16x2(h0, 0.0f) & 0xFFFF);
  }

  // xg running pointer, distance-2 prefetch pair (R8-identical per seq)
  const XG_T* xgb = xg + ((size_t)dir * M_ + (size_t)b * T_) * G4;
  const intptr_t xstep = dir ? -(intptr_t)G4 : (intptr_t)G4;
  const XG_T* xrow0 = xgb + (dir ? (size_t)(T_ - 1) * G4 : 0) + p * H_ + u;
  float xp0 = load_xg(xrow0);             // pending for sub-step t (even)
  float xp1 = load_xg(xrow0 + xstep);     // pending for sub-step t+1 (odd)
  const XG_T* xld = xrow0 + 2 * xstep;    // next load target: step t+2

  unsigned short* yp = y + ((size_t)b * T_ + (dir ? T_ - 1 : 0)) * (2 * H_)
                         + dir * H_ + u;
  const intptr_t ystep = dir ? -(intptr_t)(2 * H_) : (intptr_t)(2 * H_);

  __syncthreads();   // init h visible (full drain fine, once)

  // dot phase: reads h16[par][seq], folds xv for gate p; two 8-deep chains/gate
  auto dots = [&](int par, float xv, float& g0, float& g1, float& g2, float& g3) {
    const uint4* hv4 = (const uint4*)&h16[par][seq][0];
    uint4 h0v = hv4[4 * p + 0], h1v = hv4[4 * p + 1];
    uint4 h2v = hv4[4 * p + 2], h3v = hv4[4 * p + 3];
    half2v hh[16] = {
      u2h2(h0v.x), u2h2(h0v.y), u2h2(h0v.z), u2h2(h0v.w),
      u2h2(h1v.x), u2h2(h1v.y), u2h2(h1v.z), u2h2(h1v.w),
      u2h2(h2v.x), u2h2(h2v.y), u2h2(h2v.z), u2h2(h2v.w),
      u2h2(h3v.x), u2h2(h3v.y), u2h2(h3v.z), u2h2(h3v.w)};
    float a0 = 0, b0 = 0, a1 = 0, b1 = 0, a2 = 0, b2 = 0, a3 = 0, b3 = 0;
#pragma unroll
    for (int j = 0; j < 8; ++j) {
      a0 = fdot2(u2h2(((const unsigned int*)&wv[(0 * 16 + j) >> 2])[(0 * 16 + j) & 3]), hh[j], a0);
      a1 = fdot2(u2h2(((const unsigned int*)&wv[(1 * 16 + j) >> 2])[(1 * 16 + j) & 3]), hh[j], a1);
      a2 = fdot2(u2h2(((const unsigned int*)&wv[(2 * 16 + j) >> 2])[(2 * 16 + j) & 3]), hh[j], a2);
      a3 = fdot2(u2h2(((const unsigned int*)&wv[(3 * 16 + j) >> 2])[(3 * 16 + j) & 3]), hh[j], a3);
      int j8 = j + 8;
      b0 = fdot2(u2h2(((const unsigned int*)&wv[(0 * 16 + j8) >> 2])[(0 * 16 + j8) & 3]), hh[j8], b0);
      b1 = fdot2(u2h2(((const unsigned int*)&wv[(1 * 16 + j8) >> 2])[(1 * 16 + j8) & 3]), hh[j8], b1);
      b2 = fdot2(u2h2(((const unsigned int*)&wv[(2 * 16 + j8) >> 2])[(2 * 16 + j8) & 3]), hh[j8], b2);
      b3 = fdot2(u2h2(((const unsigned int*)&wv[(3 * 16 + j8) >> 2])[(3 * 16 + j8) & 3]), hh[j8], b3);
    }
    g0 = a0 + b0; g1 = a1 + b1; g2 = a2 + b2; g3 = a3 + b3;
    g0 += (p == 0) ? xv : 0.0f;
    g1 += (p == 1) ? xv : 0.0f;
    g2 += (p == 2) ? xv : 0.0f;
    g3 += (p == 3) ? xv : 0.0f;
  };

  auto finish = [&](int par, float g0, float g1, float g2, float g3) {
    g0 = quad_bfly_add(g0);
    g1 = quad_bfly_add(g1);
    g2 = quad_bfly_add(g2);
    g3 = quad_bfly_add(g3);
    float iv = sigm(g0), fv = sigm(g1), gv = tanh_fast(g2), ov = sigm(g3);
    c = fmaf(fv, c, iv * gv);
    float h = ov * tanh_fast(c);
    if (p == 0) {
      h16[par ^ 1][seq][u] = (unsigned short)(pack_f16x2(h, 0.0f) & 0xFFFF);
      *yp = f2bf_bits(h);
    }
    yp += ystep;
    barrier_lds_only();
  };

  for (int t = 0; t < T_; t += 2) {
    {
      float xv = xp0;
      xp0 = (t + 2 < T_) ? load_xg(xld) : 0.0f;
      xld += xstep;
      float a0, a1, a2, a3;
      dots(0, xv, a0, a1, a2, a3);
      finish(0, a0, a1, a2, a3);
    }
    {
      float xv = xp1;
      xp1 = (t + 3 < T_) ? load_xg(xld) : 0.0f;
      xld += xstep;
      float a0, a1, a2, a3;
      dots(1, xv, a0, a1, a2, a3);
      finish(1, a0, a1, a2, a3);
    }
  }
}

// ---------------------------------------------------------------------------
// Head: out[b] = y2[b, T-1, :] . lin_w + lin_b
__global__ void k_head(const unsigned short* __restrict__ y2, const float* __restrict__ lw,
                       const float* __restrict__ lb, float* __restrict__ out) {
  int b = blockIdx.x, l = threadIdx.x;
  const unsigned short* row = y2 + ((size_t)b * T_ + (T_ - 1)) * (2 * H_);
  float s = 0;
#pragma unroll
  for (int k = 0; k < 4; ++k) s += bf_bits2f(row[l + 64 * k]) * lw[l + 64 * k];
#pragma unroll
  for (int off = 32; off > 0; off >>= 1) s += __shfl_down(s, off);
  if (l == 0) out[b] = s + lb[0];
}

// ---------------------------------------------------------------------------
template <typename XG_T>
static inline void run_layers(const unsigned int* const* wfs,
                              const unsigned short* x0,
                              unsigned short* y0, unsigned short* y1, unsigned short* y2,
                              const unsigned short* wb0, const unsigned short* wb1,
                              const unsigned short* wb2,
                              const float* bias0, const float* bias1, const float* bias2,
                              const float* hx, const float* cx,
                              XG_T* xg, hipStream_t stream) {
  dim3 gg(M_ / 128, G4 / 128, 2);
  k_gemm<XG_T><<<gg, 256, 0, stream>>>(x0, wb0, bias0, xg, EMB_);
  k_scan<XG_T><<<64, 1024, 0, stream>>>(wfs[0], hx, cx, xg, y0);
  k_gemm<XG_T><<<gg, 256, 0, stream>>>(y0, wb1, bias1, xg, 2 * H_);
  k_scan<XG_T><<<64, 1024, 0, stream>>>(wfs[1], hx + 2 * B_ * H_, cx + 2 * B_ * H_, xg, y1);
  k_gemm<XG_T><<<gg, 256, 0, stream>>>(y1, wb2, bias2, xg, 2 * H_);
  k_scan<XG_T><<<64, 1024, 0, stream>>>(wfs[2], hx + 4 * B_ * H_, cx + 4 * B_ * H_, xg, y2);
}

extern "C" void kernel_launch(void* const* d_in, const int* in_sizes, int n_in,
                              void* d_out, int out_size, void* d_ws, size_t ws_size,
                              hipStream_t stream) {
  const int*   X   = (const int*)d_in[0];
  const float* emb = (const float*)d_in[1];
  const float* hx  = (const float*)d_in[2];
  const float* cx  = (const float*)d_in[3];
  const float* lw  = (const float*)d_in[4];
  const float* lb  = (const float*)d_in[5];
  const float* w_ih[3] = {(const float*)d_in[6],  (const float*)d_in[10], (const float*)d_in[14]};
  const float* w_hh[3] = {(const float*)d_in[7],  (const float*)d_in[11], (const float*)d_in[15]};
  const float* b_ih[3] = {(const float*)d_in[8],  (const float*)d_in[12], (const float*)d_in[16]};
  const float* b_hh[3] = {(const float*)d_in[9],  (const float*)d_in[13], (const float*)d_in[17]};
  float* out = (float*)d_out;

  char* ws = (char*)d_ws;
  size_t off = 0;
  auto carve = [&](size_t bytes) {
    char* p = ws + off;
    off = (off + bytes + 255) & ~(size_t)255;
    return p;
  };
  unsigned short* x0  = (unsigned short*)carve((size_t)M_ * EMB_ * 2);
  unsigned short* y0  = (unsigned short*)carve((size_t)M_ * 2 * H_ * 2);
  unsigned short* y1  = (unsigned short*)carve((size_t)M_ * 2 * H_ * 2);
  unsigned short* y2  = (unsigned short*)carve((size_t)M_ * 2 * H_ * 2);
  unsigned short* wb0 = (unsigned short*)carve((size_t)2 * G4 * EMB_ * 2);
  unsigned short* wb1 = (unsigned short*)carve((size_t)2 * G4 * 2 * H_ * 2);
  unsigned short* wb2 = (unsigned short*)carve((size_t)2 * G4 * 2 * H_ * 2);
  float* bias0 = (float*)carve(2 * G4 * 4);
  float* bias1 = (float*)carve(2 * G4 * 4);
  float* bias2 = (float*)carve(2 * G4 * 4);
  unsigned int* wf0 = (unsigned int*)carve((size_t)65536 * 4);
  unsigned int* wf1 = (unsigned int*)carve((size_t)65536 * 4);
  unsigned int* wf2 = (unsigned int*)carve((size_t)65536 * 4);
  const size_t xg_f32_bytes = (size_t)2 * M_ * G4 * 4;
  const bool use_f32 = (off + xg_f32_bytes) <= ws_size;
  void* xg = carve(use_f32 ? xg_f32_bytes : xg_f32_bytes / 2);

  k_prep<<<256, 256, 0, stream>>>(w_ih[0], b_ih[0], b_hh[0], wb0, bias0, 2 * G4 * EMB_);
  k_prep<<<256, 256, 0, stream>>>(w_ih[1], b_ih[1], b_hh[1], wb1, bias1, 2 * G4 * 2 * H_);
  k_prep<<<256, 256, 0, stream>>>(w_ih[2], b_ih[2], b_hh[2], wb2, bias2, 2 * G4 * 2 * H_);
  k_prep_whh<<<256, 256, 0, stream>>>(w_hh[0], wf0);
  k_prep_whh<<<256, 256, 0, stream>>>(w_hh[1], wf1);
  k_prep_whh<<<256, 256, 0, stream>>>(w_hh[2], wf2);
  k_gather<<<(M_ * 32) / 256, 256, 0, stream>>>(X, emb, x0);

  const unsigned int* wfs[3] = {wf0, wf1, wf2};
  if (use_f32)
    run_layers<float>(wfs, x0, y0, y1, y2, wb0, wb1, wb2, bias0, bias1, bias2,
                      hx, cx, (float*)xg, stream);
  else
    run_layers<unsigned short>(wfs, x0, y0, y1, y2, wb0, wb1, wb2, bias0, bias1, bias2,
                               hx, cx, (unsigned short*)xg, stream);

  k_head<<<64, 64, 0, stream>>>(y2, lw, lb, out);
}

// Round 12
// 1121.494 us; speedup vs baseline: 2.0574x; 2.0574x over previous
//
#include <hip/hip_runtime.h>
#include <hip/hip_bf16.h>
#include <stdint.h>

// Problem constants (LSTM_36825049596199)
#define B_    64
#define T_    512
#define EMB_  128
#define H_    128
#define G4    512            // 4*H
#define M_    (B_ * T_)      // 32768 rows for the input-projection GEMM

typedef __attribute__((ext_vector_type(8))) short     short8;   // 8 bf16 MFMA frag
typedef __attribute__((ext_vector_type(4))) float     floatx4;  // MFMA acc frag
typedef __attribute__((ext_vector_type(2))) _Float16  half2v;   // packed f16 (v_dot2)

#define GLDS(g, l) __builtin_amdgcn_global_load_lds( \
    (__attribute__((address_space(1))) void*)(g),    \
    (__attribute__((address_space(3))) void*)(l), 16, 0, 0)

__device__ __forceinline__ unsigned short f2bf_bits(float f) {
  __hip_bfloat16 h = __float2bfloat16(f);
  return *reinterpret_cast<unsigned short*>(&h);
}
__device__ __forceinline__ float bf_bits2f(unsigned short u) {
  unsigned int x = ((unsigned int)u) << 16;
  return __uint_as_float(x);
}
__device__ __forceinline__ float sigm(float x) {
  return __fdividef(1.0f, 1.0f + __expf(-x));
}
__device__ __forceinline__ float tanh_fast(float x) {
  return 1.0f - __fdividef(2.0f, __expf(2.0f * x) + 1.0f);
}

__device__ __forceinline__ unsigned int pack_f16x2(float a, float b) {
  half2v h; h.x = (_Float16)a; h.y = (_Float16)b;
  return __builtin_bit_cast(unsigned int, h);
}
__device__ __forceinline__ half2v u2h2(unsigned int u) {
  return __builtin_bit_cast(half2v, u);
}

#if __has_builtin(__builtin_amdgcn_fdot2)
__device__ __forceinline__ float fdot2(half2v a, half2v b, float c) {
  return __builtin_amdgcn_fdot2(a, b, c, false);   // v_dot2_f32_f16, fp32 acc
}
#else
__device__ __forceinline__ float fdot2(half2v a, half2v b, float c) {
  return fmaf((float)a.x, (float)b.x, fmaf((float)a.y, (float)b.y, c));
}
#endif

// Pair butterfly (lanes 2k <-> 2k+1) — single DPP stage, pure VALU.
__device__ __forceinline__ float pair_bfly_add(float x) {
  return x + __int_as_float(
      __builtin_amdgcn_mov_dpp(__float_as_int(x), 0xB1, 0xF, 0xF, true));
}

// LDS-only barrier (precise builtins; R8-verified equivalent here).
// 0xC07F: vmcnt=63, expcnt=7, lgkmcnt=0.
__device__ __forceinline__ void barrier_lds_only() {
  __builtin_amdgcn_s_waitcnt(0xC07F);
  __builtin_amdgcn_s_barrier();
}

// xg element type templated: float (precise) if workspace allows, bf16 otherwise.
__device__ __forceinline__ void  store_xg(float* p, float v)  { *p = v; }
__device__ __forceinline__ void  store_xg(unsigned short* p, float v) { *p = f2bf_bits(v); }
__device__ __forceinline__ float load_xg(const float* p)  { return *p; }
__device__ __forceinline__ float load_xg(const unsigned short* p) { return bf_bits2f(*p); }

// ---------------------------------------------------------------------------
// Embedding gather: x0[b,t,:] = bf16(emb[X[b,t],:]).
__global__ void k_gather(const int* __restrict__ X, const float* __restrict__ emb,
                         unsigned short* __restrict__ x0) {
  int i = blockIdx.x * 256 + threadIdx.x;
  int row = i >> 5, c4 = i & 31;
  float4 v = ((const float4*)emb)[(size_t)X[row] * 32 + c4];
  ushort4 o;
  o.x = f2bf_bits(v.x); o.y = f2bf_bits(v.y); o.z = f2bf_bits(v.z); o.w = f2bf_bits(v.w);
  ((ushort4*)x0)[i] = o;
}

// Per-layer prep: w_ih -> bf16, bias_sum = b_ih + b_hh.
__global__ void k_prep(const float* __restrict__ w, const float* __restrict__ bi,
                       const float* __restrict__ bh, unsigned short* __restrict__ wb,
                       float* __restrict__ bias, int nw) {
  int i = blockIdx.x * blockDim.x + threadIdx.x;
  int stride = gridDim.x * blockDim.x;
  for (int k = i; k < nw; k += stride) wb[k] = f2bf_bits(w[k]);
  for (int k = i; k < 2 * G4; k += stride) bias[k] = bi[k] + bh[k];
}

// W_hh f16-pack for the R12 4-wave scan layout (256 threads/seq):
// thread ts: lane=ts&63, w=ts>>6, p=lane&1, ul=lane>>1, u=w*32+ul.
// Lane holds d = g*32+jj (g=0..3, jj=0..31) -> f16 pair (k=64p+2jj, k+1).
// wf flat index = ((dir*32 + i4)*256 + ts)*4 + q, with d = i4*4+q.
__global__ void k_prep_whh(const float* __restrict__ Whh, unsigned int* __restrict__ wf) {
  int i = blockIdx.x * 256 + threadIdx.x;          // [0, 65536)
  int dir = i >> 15;
  int r   = i & 0x7FFF;
  int i4  = r >> 10;         // 0..31
  int r2  = r & 0x3FF;
  int ts  = r2 >> 2;         // 0..255
  int q   = r2 & 3;
  int d   = i4 * 4 + q;      // 0..127
  int g   = d >> 5;
  int jj  = d & 31;
  int lane = ts & 63, w = ts >> 6;
  int p = lane & 1, ul = lane >> 1;
  int u = w * 32 + ul;
  int k = 64 * p + 2 * jj;
  const float* wr = Whh + ((size_t)dir * G4 + g * H_ + u) * H_ + k;
  wf[i] = pack_f16x2(wr[0], wr[1]);
}

// ---------------------------------------------------------------------------
// Input-projection GEMM (NT) — unchanged (m97-style, gate-major xg columns).
template <typename XG_T>
__global__ __launch_bounds__(256, 2) void k_gemm(
    const unsigned short* __restrict__ A,   // [M_, K] bf16 row-major
    const unsigned short* __restrict__ W,   // [2][G4][K] bf16 row-major
    const float* __restrict__ bias,         // [2][G4]
    XG_T* __restrict__ xg,                  // [2][M_][G4]
    int K) {
  __shared__ unsigned short sA[128 * 32];
  __shared__ unsigned short sB[128 * 32];
  const int tid  = threadIdx.x;
  const int lane = tid & 63;
  const int wave = tid >> 6;
  const int mt = blockIdx.x, nt = blockIdx.y, dir = blockIdx.z;
  const size_t Arow0 = (size_t)mt * 128;
  const int    Ncol0 = nt * 128;
  const unsigned short* Wd = W + (size_t)dir * G4 * K;

  const int srow = tid >> 2;
  const int qlog = (tid & 3) ^ ((tid >> 4) & 3);
  auto ldsA0 = (__attribute__((address_space(3))) void*)(sA + wave * 512);
  auto ldsA1 = (__attribute__((address_space(3))) void*)(sA + 2048 + wave * 512);
  auto ldsB0 = (__attribute__((address_space(3))) void*)(sB + wave * 512);
  auto ldsB1 = (__attribute__((address_space(3))) void*)(sB + 2048 + wave * 512);

  floatx4 acc[4][4];
#pragma unroll
  for (int i = 0; i < 4; ++i)
#pragma unroll
    for (int j = 0; j < 4; ++j) acc[i][j] = (floatx4)0.0f;

  const int wrow = (wave >> 1) * 64, wcol = (wave & 1) * 64;
  const int frow = lane & 15;
  const int fq   = lane >> 4;

  for (int kt = 0; kt < K; kt += 32) {
    const unsigned short* gA0 = A  + (Arow0 + srow) * (size_t)K + kt + qlog * 8;
    const unsigned short* gB0 = Wd + (size_t)(Ncol0 + srow) * K + kt + qlog * 8;
    GLDS(gA0, ldsA0);
    GLDS(gA0 + (size_t)64 * K, ldsA1);
    GLDS(gB0, ldsB0);
    GLDS(gB0 + (size_t)64 * K, ldsB1);
    __syncthreads();

    short8 af[4], bf[4];
#pragma unroll
    for (int i = 0; i < 4; ++i) {
      int r  = wrow + 16 * i + frow;
      int rn = wcol + 16 * i + frow;
      af[i] = *(const short8*)(sA + r  * 32 + ((fq ^ ((r  >> 2) & 3)) * 8));
      bf[i] = *(const short8*)(sB + rn * 32 + ((fq ^ ((rn >> 2) & 3)) * 8));
    }
#pragma unroll
    for (int i = 0; i < 4; ++i)
#pragma unroll
      for (int j = 0; j < 4; ++j)
        acc[i][j] = __builtin_amdgcn_mfma_f32_16x16x32_bf16(af[i], bf[j], acc[i][j], 0, 0, 0);
    __syncthreads();
  }

  const int r0 = (lane >> 4) * 4;
  const int cc = lane & 15;
  XG_T* xgd = xg + (size_t)dir * M_ * G4;
#pragma unroll
  for (int j = 0; j < 4; ++j) {
    int gcol = Ncol0 + wcol + 16 * j + cc;
    float bs = bias[dir * G4 + gcol];
#pragma unroll
    for (int i = 0; i < 4; ++i) {
      size_t rowb = Arow0 + wrow + 16 * i + r0;
#pragma unroll
      for (int r = 0; r < 4; ++r)
        store_xg(&xgd[(rowb + r) * G4 + gcol], acc[i][j][r] + bs);
    }
  }
}

// ---------------------------------------------------------------------------
// Recurrent scan — R12: 4 waves (256 thr), 1 wave/SIMD, 2-way k-split.
// R11 failed by spilling (1024 thr -> VGPR 52). This round tests the LAST
// structural variable: wave count. vs R8 (8 waves, 2/SIMD): barrier spans 4
// waves not 8, zero same-SIMD wave contention, single-stage DPP reduce.
// lane = (ul=lane>>1, p=lane&1); u = wave*32 + ul; per-lane weights =
// 4 gates x 64 k (k in [64p,64p+64)) = 128 f16-dwords, VGPR-resident at
// waves_per_eu(1,1) (grid=128 blocks = 1 block/CU, so occupancy is moot).
// Per step: 8x ds_read_b128 h slice (2 unique addrs/inst -> free), 128 fdot2
// (8 chains), xg fold (2 gates/lane, 2 loads, distance-2 prefetch), 1 DPP
// pair-reduce, nonlins replicated x2, p==0 writes h+y, lgkm-only barrier.
template <typename XG_T>
__global__ __attribute__((amdgpu_flat_work_group_size(256, 256),
                          amdgpu_waves_per_eu(1, 1))) void k_scan(
    const unsigned int* __restrict__ wf,  // [2][32][256][4] packed f16 pairs
    const float* __restrict__ hx0,        // [2][B_][H_] (layer base)
    const float* __restrict__ cx0,
    const XG_T* __restrict__ xg,          // [2][M_][G4] gate-major
    unsigned short* __restrict__ y)       // [B_][T_][2*H_] bf16
{
  const int b   = blockIdx.x & 63;
  const int dir = blockIdx.x >> 6;
  const int tid = threadIdx.x;
  const int lane = tid & 63;
  const int wave = tid >> 6;
  const int p  = lane & 1;        // k-half (64 k each)
  const int ul = lane >> 1;       // unit within wave (0..31)
  const int u  = wave * 32 + ul;

  __shared__ __align__(16) unsigned short h16[2][128];

  // Weights: 32 coalesced uint4 loads; d = g*32+jj -> wv[d>>2][d&3] = f16
  // pair (k=64p+2jj, k+1) of gate g for unit u.
  uint4 wv[32];
  const uint4* wfv = (const uint4*)wf;
#pragma unroll
  for (int i = 0; i < 32; ++i) wv[i] = wfv[(dir * 32 + i) * 256 + tid];

  float c = cx0[(size_t)dir * B_ * H_ + b * H_ + u];   // replicated over pair
  if (p == 0) {
    float h0 = hx0[(size_t)dir * B_ * H_ + b * H_ + u];
    h16[0][u] = (unsigned short)(pack_f16x2(h0, 0.0f) & 0xFFFF);
  }

  // xg: lane folds gates 2p and 2p+1 for unit u; distance-2 prefetch.
  const XG_T* xgb = xg + ((size_t)dir * M_ + (size_t)b * T_) * G4;
  const intptr_t xstep = dir ? -(intptr_t)G4 : (intptr_t)G4;
  const int o0 = (2 * p) * H_ + u;          // gate 2p
  const int o1 = o0 + H_;                   // gate 2p+1
  const XG_T* xrow0 = xgb + (dir ? (size_t)(T_ - 1) * G4 : 0);
  float xa0 = load_xg(xrow0 + o0), xb0 = load_xg(xrow0 + o1);            // step t
  float xa1 = load_xg(xrow0 + xstep + o0), xb1 = load_xg(xrow0 + xstep + o1); // t+1
  const XG_T* xld = xrow0 + 2 * xstep;      // next load target: step t+2

  unsigned short* yp = y + ((size_t)b * T_ + (dir ? T_ - 1 : 0)) * (2 * H_)
                         + dir * H_ + u;
  const intptr_t ystep = dir ? -(intptr_t)(2 * H_) : (intptr_t)(2 * H_);

  __syncthreads();   // init h visible (full drain fine, once)

  // dot phase: reads h16[par] slice [64p,64p+64), folds xg pair, 8 chains.
  auto dots = [&](int par, float xva, float xvb,
                  float& g0, float& g1, float& g2, float& g3) {
    const uint4* hv4 = (const uint4*)&h16[par][0];
    uint4 hq[8];
#pragma unroll
    for (int i = 0; i < 8; ++i) hq[i] = hv4[8 * p + i];
    half2v hh[32];
#pragma unroll
    for (int i = 0; i < 8; ++i) {
      hh[4 * i + 0] = u2h2(hq[i].x);
      hh[4 * i + 1] = u2h2(hq[i].y);
      hh[4 * i + 2] = u2h2(hq[i].z);
      hh[4 * i + 3] = u2h2(hq[i].w);
    }
    float A0 = 0, B0 = 0, A1 = 0, B1 = 0, A2 = 0, B2 = 0, A3 = 0, B3 = 0;
#pragma unroll
    for (int j = 0; j < 16; ++j) {
      int d0 = j, d1 = j + 16;
      A0 = fdot2(u2h2(((const unsigned int*)&wv[(0 * 32 + d0) >> 2])[(0 * 32 + d0) & 3]), hh[d0], A0);
      A1 = fdot2(u2h2(((const unsigned int*)&wv[(1 * 32 + d0) >> 2])[(1 * 32 + d0) & 3]), hh[d0], A1);
      A2 = fdot2(u2h2(((const unsigned int*)&wv[(2 * 32 + d0) >> 2])[(2 * 32 + d0) & 3]), hh[d0], A2);
      A3 = fdot2(u2h2(((const unsigned int*)&wv[(3 * 32 + d0) >> 2])[(3 * 32 + d0) & 3]), hh[d0], A3);
      B0 = fdot2(u2h2(((const unsigned int*)&wv[(0 * 32 + d1) >> 2])[(0 * 32 + d1) & 3]), hh[d1], B0);
      B1 = fdot2(u2h2(((const unsigned int*)&wv[(1 * 32 + d1) >> 2])[(1 * 32 + d1) & 3]), hh[d1], B1);
      B2 = fdot2(u2h2(((const unsigned int*)&wv[(2 * 32 + d1) >> 2])[(2 * 32 + d1) & 3]), hh[d1], B2);
      B3 = fdot2(u2h2(((const unsigned int*)&wv[(3 * 32 + d1) >> 2])[(3 * 32 + d1) & 3]), hh[d1], B3);
    }
    g0 = A0 + B0; g1 = A1 + B1; g2 = A2 + B2; g3 = A3 + B3;
    // fold xg: lane p holds xg for gates 2p, 2p+1 (added once across pair)
    g0 += (p == 0) ? xva : 0.0f;
    g1 += (p == 0) ? xvb : 0.0f;
    g2 += (p == 1) ? xva : 0.0f;
    g3 += (p == 1) ? xvb : 0.0f;
  };

  auto finish = [&](int par, float g0, float g1, float g2, float g3) {
    g0 = pair_bfly_add(g0);
    g1 = pair_bfly_add(g1);
    g2 = pair_bfly_add(g2);
    g3 = pair_bfly_add(g3);
    float iv = sigm(g0), fv = sigm(g1), gv = tanh_fast(g2), ov = sigm(g3);
    c = fmaf(fv, c, iv * gv);
    float h = ov * tanh_fast(c);
    if (p == 0) {
      h16[par ^ 1][u] = (unsigned short)(pack_f16x2(h, 0.0f) & 0xFFFF);
      *yp = f2bf_bits(h);
    }
    yp += ystep;
    barrier_lds_only();
  };

  for (int t = 0; t < T_; t += 2) {
    {
      float va = xa0, vb = xb0;
      if (t + 2 < T_) { xa0 = load_xg(xld + o0); xb0 = load_xg(xld + o1); }
      else            { xa0 = 0.0f; xb0 = 0.0f; }
      xld += xstep;
      float a0, a1, a2, a3;
      dots(0, va, vb, a0, a1, a2, a3);
      finish(0, a0, a1, a2, a3);
    }
    {
      float va = xa1, vb = xb1;
      if (t + 3 < T_) { xa1 = load_xg(xld + o0); xb1 = load_xg(xld + o1); }
      else            { xa1 = 0.0f; xb1 = 0.0f; }
      xld += xstep;
      float a0, a1, a2, a3;
      dots(1, va, vb, a0, a1, a2, a3);
      finish(1, a0, a1, a2, a3);
    }
  }
}

// ---------------------------------------------------------------------------
// Head: out[b] = y2[b, T-1, :] . lin_w + lin_b
__global__ void k_head(const unsigned short* __restrict__ y2, const float* __restrict__ lw,
                       const float* __restrict__ lb, float* __restrict__ out) {
  int b = blockIdx.x, l = threadIdx.x;
  const unsigned short* row = y2 + ((size_t)b * T_ + (T_ - 1)) * (2 * H_);
  float s = 0;
#pragma unroll
  for (int k = 0; k < 4; ++k) s += bf_bits2f(row[l + 64 * k]) * lw[l + 64 * k];
#pragma unroll
  for (int off = 32; off > 0; off >>= 1) s += __shfl_down(s, off);
  if (l == 0) out[b] = s + lb[0];
}

// ---------------------------------------------------------------------------
template <typename XG_T>
static inline void run_layers(const unsigned int* const* wfs,
                              const unsigned short* x0,
                              unsigned short* y0, unsigned short* y1, unsigned short* y2,
                              const unsigned short* wb0, const unsigned short* wb1,
                              const unsigned short* wb2,
                              const float* bias0, const float* bias1, const float* bias2,
                              const float* hx, const float* cx,
                              XG_T* xg, hipStream_t stream) {
  dim3 gg(M_ / 128, G4 / 128, 2);
  k_gemm<XG_T><<<gg, 256, 0, stream>>>(x0, wb0, bias0, xg, EMB_);
  k_scan<XG_T><<<128, 256, 0, stream>>>(wfs[0], hx, cx, xg, y0);
  k_gemm<XG_T><<<gg, 256, 0, stream>>>(y0, wb1, bias1, xg, 2 * H_);
  k_scan<XG_T><<<128, 256, 0, stream>>>(wfs[1], hx + 2 * B_ * H_, cx + 2 * B_ * H_, xg, y1);
  k_gemm<XG_T><<<gg, 256, 0, stream>>>(y1, wb2, bias2, xg, 2 * H_);
  k_scan<XG_T><<<128, 256, 0, stream>>>(wfs[2], hx + 4 * B_ * H_, cx + 4 * B_ * H_, xg, y2);
}

extern "C" void kernel_launch(void* const* d_in, const int* in_sizes, int n_in,
                              void* d_out, int out_size, void* d_ws, size_t ws_size,
                              hipStream_t stream) {
  const int*   X   = (const int*)d_in[0];
  const float* emb = (const float*)d_in[1];
  const float* hx  = (const float*)d_in[2];
  const float* cx  = (const float*)d_in[3];
  const float* lw  = (const float*)d_in[4];
  const float* lb  = (const float*)d_in[5];
  const float* w_ih[3] = {(const float*)d_in[6],  (const float*)d_in[10], (const float*)d_in[14]};
  const float* w_hh[3] = {(const float*)d_in[7],  (const float*)d_in[11], (const float*)d_in[15]};
  const float* b_ih[3] = {(const float*)d_in[8],  (const float*)d_in[12], (const float*)d_in[16]};
  const float* b_hh[3] = {(const float*)d_in[9],  (const float*)d_in[13], (const float*)d_in[17]};
  float* out = (float*)d_out;

  char* ws = (char*)d_ws;
  size_t off = 0;
  auto carve = [&](size_t bytes) {
    char* p = ws + off;
    off = (off + bytes + 255) & ~(size_t)255;
    return p;
  };
  unsigned short* x0  = (unsigned short*)carve((size_t)M_ * EMB_ * 2);
  unsigned short* y0  = (unsigned short*)carve((size_t)M_ * 2 * H_ * 2);
  unsigned short* y1  = (unsigned short*)carve((size_t)M_ * 2 * H_ * 2);
  unsigned short* y2  = (unsigned short*)carve((size_t)M_ * 2 * H_ * 2);
  unsigned short* wb0 = (unsigned short*)carve((size_t)2 * G4 * EMB_ * 2);
  unsigned short* wb1 = (unsigned short*)carve((size_t)2 * G4 * 2 * H_ * 2);
  unsigned short* wb2 = (unsigned short*)carve((size_t)2 * G4 * 2 * H_ * 2);
  float* bias0 = (float*)carve(2 * G4 * 4);
  float* bias1 = (float*)carve(2 * G4 * 4);
  float* bias2 = (float*)carve(2 * G4 * 4);
  unsigned int* wf0 = (unsigned int*)carve((size_t)65536 * 4);
  unsigned int* wf1 = (unsigned int*)carve((size_t)65536 * 4);
  unsigned int* wf2 = (unsigned int*)carve((size_t)65536 * 4);
  const size_t xg_f32_bytes = (size_t)2 * M_ * G4 * 4;
  const bool use_f32 = (off + xg_f32_bytes) <= ws_size;
  void* xg = carve(use_f32 ? xg_f32_bytes : xg_f32_bytes / 2);

  k_prep<<<256, 256, 0, stream>>>(w_ih[0], b_ih[0], b_hh[0], wb0, bias0, 2 * G4 * EMB_);
  k_prep<<<256, 256, 0, stream>>>(w_ih[1], b_ih[1], b_hh[1], wb1, bias1, 2 * G4 * 2 * H_);
  k_prep<<<256, 256, 0, stream>>>(w_ih[2], b_ih[2], b_hh[2], wb2, bias2, 2 * G4 * 2 * H_);
  k_prep_whh<<<256, 256, 0, stream>>>(w_hh[0], wf0);
  k_prep_whh<<<256, 256, 0, stream>>>(w_hh[1], wf1);
  k_prep_whh<<<256, 256, 0, stream>>>(w_hh[2], wf2);
  k_gather<<<(M_ * 32) / 256, 256, 0, stream>>>(X, emb, x0);

  const unsigned int* wfs[3] = {wf0, wf1, wf2};
  if (use_f32)
    run_layers<float>(wfs, x0, y0, y1, y2, wb0, wb1, wb2, bias0, bias1, bias2,
                      hx, cx, (float*)xg, stream);
  else
    run_layers<unsigned short>(wfs, x0, y0, y1, y2, wb0, wb1, wb2, bias0, bias1, bias2,
                               hx, cx, (unsigned short*)xg, stream);

  k_head<<<64, 64, 0, stream>>>(y2, lw, lb, out);
}